// Round 1
// 995.038 us; speedup vs baseline: 1.1597x; 1.1597x over previous
//
#include <hip/hip_runtime.h>
#include <stdint.h>

#define B_ 32
#define S_ 128
#define T_ 128
#define V_ 32000
#define E_ 256
#define H_ 256
#define NEG_ (-1.0e9f)

typedef __attribute__((ext_vector_type(8))) short short8;
typedef __attribute__((ext_vector_type(4))) float floatx4;

__device__ __forceinline__ unsigned short f2bf(float x){
  unsigned u = __float_as_uint(x);
  u = u + 0x7fffu + ((u >> 16) & 1u);   // RNE
  return (unsigned short)(u >> 16);
}
__device__ __forceinline__ float bf2f(unsigned short s){
  return __uint_as_float(((unsigned)s) << 16);
}
__device__ __forceinline__ float hsum4(float4 v){ return (v.x+v.y)+(v.z+v.w); }
__device__ __forceinline__ void unpack8(uint4 q, float4& lo, float4& hi){
  lo.x = __uint_as_float(q.x << 16); lo.y = __uint_as_float(q.x & 0xffff0000u);
  lo.z = __uint_as_float(q.y << 16); lo.w = __uint_as_float(q.y & 0xffff0000u);
  hi.x = __uint_as_float(q.z << 16); hi.y = __uint_as_float(q.z & 0xffff0000u);
  hi.z = __uint_as_float(q.w << 16); hi.w = __uint_as_float(q.w & 0xffff0000u);
}

// async global->LDS, 16B per lane (wave-uniform LDS base + lane*16 rule)
#define GLOAD_LDS16(gptr, lptr) \
  __builtin_amdgcn_global_load_lds( \
      (const __attribute__((address_space(1))) unsigned int*)(const void*)(gptr), \
      (__attribute__((address_space(3))) unsigned int*)(void*)(lptr), 16, 0, 0)

// ---------------- fp32 -> bf16 array conversion ----------------
__global__ void k_cvt(const float* __restrict__ src, unsigned short* __restrict__ dst, int n4){
  int i = blockIdx.x*256 + threadIdx.x;
  if (i < n4){
    float4 v = ((const float4*)src)[i];
    ushort4 o; o.x=f2bf(v.x); o.y=f2bf(v.y); o.z=f2bf(v.z); o.w=f2bf(v.w);
    ((ushort4*)dst)[i] = o;
  }
}

// ---------------- Xih = emb[idx] @ W_ih^T + b_ih + b_hh  (parallel over b,t) ----
// grid: 32 b * 8 t-tiles = 256 blocks, 256 threads
__global__ __launch_bounds__(256) void k_xih(
    const int* __restrict__ idxmat,   // [B][128]
    const float* __restrict__ emb,    // [V][E]
    const float* __restrict__ Wih,    // [H][E]
    const float* __restrict__ b1, const float* __restrict__ b2,
    float* __restrict__ out)          // [B][128][H]
{
  __shared__ int idx_s[16];
  __shared__ float4 x_s[16][64];      // 16 rows x 256 f32
  int b = blockIdx.x >> 3;
  int t0 = (blockIdx.x & 7) << 4;
  int tid = threadIdx.x;
  if (tid < 16) idx_s[tid] = idxmat[b*128 + t0 + tid];
  __syncthreads();
  for (int r = 0; r < 16; ++r)
    ((float*)&x_s[r][0])[tid] = emb[(size_t)idx_s[r]*E_ + tid];
  __syncthreads();
  int j2 = tid & 127, tg = tid >> 7;             // thread -> rows {j2, j2+128}, 8 t's
  const float4* W0 = (const float4*)(Wih + (size_t)j2*E_);
  const float4* W1 = (const float4*)(Wih + (size_t)(j2+128)*E_);
  float4 a0[8], a1[8];
  #pragma unroll
  for (int t=0;t<8;++t){ a0[t]={0,0,0,0}; a1[t]={0,0,0,0}; }
  for (int e4 = 0; e4 < 64; ++e4){
    float4 w0 = W0[e4], w1 = W1[e4];
    #pragma unroll
    for (int t = 0; t < 8; ++t){
      float4 xv = x_s[tg*8+t][e4];               // LDS broadcast
      a0[t] += w0*xv; a1[t] += w1*xv;
    }
  }
  float bi0 = b1[j2] + b2[j2];
  float bi1 = b1[j2+128] + b2[j2+128];
  #pragma unroll
  for (int t = 0; t < 8; ++t){
    size_t row = (size_t)((b<<7) + t0 + tg*8 + t)*H_;
    out[row + j2]     = hsum4(a0[t]) + bi0;
    out[row + j2+128] = hsum4(a1[t]) + bi1;
  }
}

// ---------------- sequential RNN recurrence, one block per batch row ----------
// ENC=1: h frozen past length, writes bf16 enc_out (0 at pad) + hfinal.
// ENC=0: plain tanh cell, writes f32 h sequence.
template<int ENC>
__global__ __launch_bounds__(512, 2) void k_rnn(
    const float* __restrict__ Whh,    // [H][H]
    const float* __restrict__ Xih,    // [B][128][H], biases already included
    const float* __restrict__ h0,     // dec: [B][H]
    const int* __restrict__ lengths,  // enc
    unsigned short* __restrict__ enc_out, // enc: bf16 [B][S][H]
    float* __restrict__ hseq,         // dec: [B][T][H]
    float* __restrict__ hfinal)       // enc: [B][H]
{
  __shared__ float4 h4_s[64];         // h, 256 f32
  __shared__ float part[2][256];
  float* h_s = (float*)h4_s;
  int b = blockIdx.x, tid = threadIdx.x;
  int j = tid & 255, half = tid >> 8; // output row j, K-half
  float4 w[32];                       // W_hh[j][half*128 .. +128) resident in VGPRs
  const float4* Wr = (const float4*)(Whh + (size_t)j*H_ + half*128);
  #pragma unroll
  for (int i = 0; i < 32; ++i) w[i] = Wr[i];
  if (tid < 256) h_s[tid] = ENC ? 0.f : h0[b*H_ + tid];
  int len = ENC ? lengths[b] : T_;
  __syncthreads();
  for (int t = 0; t < 128; ++t){
    float x = 0.f;
    if (tid < 256) x = Xih[(size_t)((b<<7) + t)*H_ + j];   // issued early, used after barrier
    const float4* hh = h4_s + (half << 5);
    float4 acc0 = {0,0,0,0}, acc1 = {0,0,0,0};
    #pragma unroll
    for (int i = 0; i < 32; i += 2){ acc0 += w[i]*hh[i]; acc1 += w[i+1]*hh[i+1]; }
    part[half][j] = hsum4(acc0) + hsum4(acc1);
    __syncthreads();
    if (tid < 256){
      float s = x + part[0][tid] + part[1][tid];
      float hn = tanhf(s);
      if (ENC){
        float hold = h_s[tid];
        bool v = (t < len);
        h_s[tid] = v ? hn : hold;
        enc_out[(size_t)((b<<7)+t)*H_ + tid] = f2bf(v ? hn : 0.f);
      } else {
        h_s[tid] = hn;
        hseq[(size_t)((b<<7)+t)*H_ + tid] = hn;
      }
    }
    __syncthreads();
  }
  if (ENC && tid < 256) hfinal[b*H_ + tid] = h_s[tid];
}

// ---------------- attention + combine (parallel over b, t-tiles of 16) --------
// grid: 32*8 = 256 blocks, 256 threads
__global__ __launch_bounds__(256) void k_attn(
    const unsigned short* __restrict__ enc_out, // bf16 [B][S][H]
    const float* __restrict__ hseq,             // [B][T][H]
    const int* __restrict__ lengths,
    const unsigned short* __restrict__ Wattn,   // bf16 [H][2H]
    const float* __restrict__ battn,            // [H]
    unsigned short* __restrict__ attn_out)      // bf16 [B*T][H]
{
  __shared__ float h_sm[16][256];   // 16 KB
  __shared__ float sc[16][132];     // 8.25 KB (pad 4)
  __shared__ float comb[16][512];   // 32 KB : [context | h]
  int bx = blockIdx.x; int b = bx >> 3; int t0 = (bx & 7) << 4;
  int tid = threadIdx.x;
  int len = lengths[b];
  for (int r = 0; r < 16; ++r)
    h_sm[r][tid] = hseq[(size_t)((b<<7) + t0 + r)*H_ + tid];
  __syncthreads();
  // phase 1: scores[t][s] = h_t . enc_s   (enc read from global, L1/L2-hot)
  {
    int s = tid & 127, tg = tid >> 7;
    float4 a[8];
    #pragma unroll
    for (int t=0;t<8;++t) a[t] = {0,0,0,0};
    const uint4* ep = (const uint4*)(enc_out + (size_t)(b*S_ + s)*H_);
    for (int oct = 0; oct < 32; ++oct){
      uint4 q = ep[oct];
      float4 elo, ehi; unpack8(q, elo, ehi);
      #pragma unroll
      for (int t = 0; t < 8; ++t){
        const float4* hp = (const float4*)&h_sm[tg*8+t][oct*8]; // broadcast
        a[t] += elo*hp[0] + ehi*hp[1];
      }
    }
    #pragma unroll
    for (int t = 0; t < 8; ++t)
      sc[tg*8+t][s] = (s < len) ? hsum4(a[t]) : NEG_;
  }
  __syncthreads();
  // phase 2: softmax per row, one wave per row, 4 rounds
  {
    int wv = tid >> 6, ln = tid & 63;
    for (int r = 0; r < 4; ++r){
      int t = r*4 + wv;
      float v0 = sc[t][ln], v1 = sc[t][ln+64];
      float m = fmaxf(v0, v1);
      #pragma unroll
      for (int off = 32; off >= 1; off >>= 1) m = fmaxf(m, __shfl_xor(m, off));
      float e0 = __expf(v0 - m), e1 = __expf(v1 - m);
      float su = e0 + e1;
      #pragma unroll
      for (int off = 32; off >= 1; off >>= 1) su += __shfl_xor(su, off);
      float inv = 1.0f / su;
      sc[t][ln] = e0*inv; sc[t][ln+64] = e1*inv;
    }
  }
  __syncthreads();
  // phase 3: context[t][hd] = sum_s attn[t][s]*enc[s][hd]  -> comb[:, 0:256]
  {
    int hd = tid & 127, tg = tid >> 7;
    float c0[8], c1[8];
    #pragma unroll
    for (int t=0;t<8;++t){ c0[t]=0.f; c1[t]=0.f; }
    for (int s4 = 0; s4 < 32; ++s4){
      float ea[4], eb[4];
      #pragma unroll
      for (int i = 0; i < 4; ++i){
        const unsigned short* er = enc_out + (size_t)(b*S_ + s4*4 + i)*H_;
        ea[i] = bf2f(er[hd]); eb[i] = bf2f(er[hd+128]);
      }
      #pragma unroll
      for (int t = 0; t < 8; ++t){
        float4 av = *(const float4*)&sc[tg*8+t][s4*4];   // broadcast
        c0[t] += av.x*ea[0] + av.y*ea[1] + av.z*ea[2] + av.w*ea[3];
        c1[t] += av.x*eb[0] + av.y*eb[1] + av.z*eb[2] + av.w*eb[3];
      }
    }
    #pragma unroll
    for (int t = 0; t < 8; ++t){
      comb[tg*8+t][hd]     = c0[t];
      comb[tg*8+t][hd+128] = c1[t];
    }
  }
  for (int r = 0; r < 16; ++r) comb[r][256 + tid] = h_sm[r][tid];
  __syncthreads();
  // phase 4: attn_out[t][j] = tanh(b_attn[j] + W_attn[j][:] . comb[t][:])
  {
    int j2 = tid & 127, tg = tid >> 7;
    float4 a0[8], a1[8];
    #pragma unroll
    for (int t=0;t<8;++t){ a0[t]={0,0,0,0}; a1[t]={0,0,0,0}; }
    const uint4* W0 = (const uint4*)(Wattn + (size_t)j2*512);
    const uint4* W1 = (const uint4*)(Wattn + (size_t)(j2+128)*512);
    for (int oct = 0; oct < 64; ++oct){
      float4 w0lo, w0hi, w1lo, w1hi;
      unpack8(W0[oct], w0lo, w0hi);
      unpack8(W1[oct], w1lo, w1hi);
      #pragma unroll
      for (int t = 0; t < 8; ++t){
        const float4* cp = (const float4*)&comb[tg*8+t][oct*8]; // broadcast
        float4 clo = cp[0], chi = cp[1];
        a0[t] += w0lo*clo + w0hi*chi;
        a1[t] += w1lo*clo + w1hi*chi;
      }
    }
    float bi0 = battn[j2], bi1 = battn[j2+128];
    #pragma unroll
    for (int t = 0; t < 8; ++t){
      size_t row = (size_t)((b<<7) + t0 + tg*8 + t)*H_;
      attn_out[row + j2]     = f2bf(tanhf(hsum4(a0[t]) + bi0));
      attn_out[row + j2+128] = f2bf(tanhf(hsum4(a1[t]) + bi1));
    }
  }
}

// ---------------- vocab projection: [4096,256]bf16 @ W_out^T -> fp32 ----------
// m97-style LDS-staged GEMM: 128x128 tile, BK=32, double-buffered LDS (32 KB),
// global_load_lds width=16 staging, 4 waves x (64x64) = 4x4 frags of 16x16x32.
// LDS read swizzle: slot = lhi ^ ((row>>1)&3), with the inverse applied on the
// GLOBAL source slot (linear LDS dest, per rule "both-sides-or-neither").
__global__ __launch_bounds__(256) void k_vocab(
    const unsigned short* __restrict__ A,   // attn_out bf16 [4096][256]
    const unsigned short* __restrict__ Wb,  // W_out bf16 [V][256]
    const float* __restrict__ bout,         // [V]
    float* __restrict__ out)                // [4096][V]
{
  __shared__ unsigned short Asm[2][128*32];  // 8 KB per buffer
  __shared__ unsigned short Bsm[2][128*32];
  int nb = blockIdx.x, mb = blockIdx.y;
  int tid = threadIdx.x;
  int ln  = tid & 63;
  int wid = tid >> 6;
  int llo = ln & 15, lhi = ln >> 4;
  int wr = wid >> 1, wc = wid & 1;          // wave -> 64x64 sub-tile (wr*64, wc*64)
  int mbase = mb*128, nbase = nb*128;

  // staging: 512 chunks of 16B per operand tile; thread owns chunks {tid, tid+256}
  // chunk c: row = c>>2, dest slot rb = c&3, source k-slot = rb ^ ((row>>1)&3)
  int c0 = tid, c1 = tid + 256;
  int r0 = c0 >> 2, s0 = (c0 & 3) ^ ((r0 >> 1) & 3);
  int r1 = c1 >> 2, s1 = (c1 & 3) ^ ((r1 >> 1) & 3);
  const unsigned short* Ag0 = A  + (size_t)(mbase + r0)*256 + s0*8;
  const unsigned short* Ag1 = A  + (size_t)(mbase + r1)*256 + s1*8;
  const unsigned short* Bg0 = Wb + (size_t)(nbase + r0)*256 + s0*8;
  const unsigned short* Bg1 = Wb + (size_t)(nbase + r1)*256 + s1*8;

#define STAGE_V(bufi, kk) do { \
    GLOAD_LDS16(Ag0 + (kk), &Asm[bufi][c0*8]); \
    GLOAD_LDS16(Ag1 + (kk), &Asm[bufi][c1*8]); \
    GLOAD_LDS16(Bg0 + (kk), &Bsm[bufi][c0*8]); \
    GLOAD_LDS16(Bg1 + (kk), &Bsm[bufi][c1*8]); \
  } while(0)

  floatx4 acc[4][4];
  #pragma unroll
  for (int mi=0;mi<4;++mi)
    #pragma unroll
    for (int ni=0;ni<4;++ni) acc[mi][ni] = (floatx4){0.f,0.f,0.f,0.f};

  // precomputed swizzled read offsets (element units); rows are multiples of 16
  // so the XOR term depends only on llo: q = (llo>>1)&3
  int q = (llo >> 1) & 3;
  int aoff[4], boff[4];
  #pragma unroll
  for (int i=0;i<4;++i){
    int arow = wr*64 + i*16 + llo;
    aoff[i] = arow*32 + ((lhi ^ q)*8);
    int brow = wc*64 + i*16 + llo;
    boff[i] = brow*32 + ((lhi ^ q)*8);
  }

  STAGE_V(0, 0);
  __syncthreads();                         // drains vmcnt + barrier

  #pragma unroll
  for (int k0 = 0; k0 < 8; ++k0){
    int cur = k0 & 1;
    if (k0 < 7) STAGE_V(cur^1, (k0+1)*32); // prefetch next K-tile
    short8 afr[4];
    #pragma unroll
    for (int mi=0;mi<4;++mi)
      afr[mi] = *(const short8*)&Asm[cur][aoff[mi]];
    #pragma unroll
    for (int ni=0;ni<4;++ni){
      short8 bfr = *(const short8*)&Bsm[cur][boff[ni]];
      #pragma unroll
      for (int mi=0;mi<4;++mi)
        acc[mi][ni] = __builtin_amdgcn_mfma_f32_16x16x32_bf16(afr[mi], bfr, acc[mi][ni], 0, 0, 0);
    }
    __syncthreads();
  }

  // epilogue: C/D layout col=lane&15, row=(lane>>4)*4+r
  #pragma unroll
  for (int ni = 0; ni < 4; ++ni){
    int col = nbase + wc*64 + ni*16 + llo;
    float bias = bout[col];
    #pragma unroll
    for (int mi = 0; mi < 4; ++mi){
      #pragma unroll
      for (int r = 0; r < 4; ++r){
        int row = mbase + wr*64 + mi*16 + lhi*4 + r;
        out[(size_t)row*V_ + col] = acc[mi][ni][r] + bias;
      }
    }
  }
#undef STAGE_V
}

extern "C" void kernel_launch(void* const* d_in, const int* in_sizes, int n_in,
                              void* d_out, int out_size, void* d_ws, size_t ws_size,
                              hipStream_t stream){
  const int*   indices_de = (const int*)d_in[0];
  const int*   lengths_de = (const int*)d_in[1];
  const int*   indices_en = (const int*)d_in[2];
  const float* emb_enc   = (const float*)d_in[4];
  const float* emb_dec   = (const float*)d_in[5];
  const float* W_ih_enc  = (const float*)d_in[6];
  const float* W_hh_enc  = (const float*)d_in[7];
  const float* b_ih_enc  = (const float*)d_in[8];
  const float* b_hh_enc  = (const float*)d_in[9];
  const float* W_ih_dec  = (const float*)d_in[10];
  const float* W_hh_dec  = (const float*)d_in[11];
  const float* b_ih_dec  = (const float*)d_in[12];
  const float* b_hh_dec  = (const float*)d_in[13];
  const float* W_attn    = (const float*)d_in[14];
  const float* b_attn    = (const float*)d_in[15];
  const float* W_out     = (const float*)d_in[16];
  const float* b_out     = (const float*)d_in[17];

  char* ws = (char*)d_ws;
  size_t o = 0;
  float* Xih_enc = (float*)(ws + o); o += (size_t)4096*256*4;
  float* Xih_dec = (float*)(ws + o); o += (size_t)4096*256*4;
  unsigned short* enc_bf = (unsigned short*)(ws + o); o += (size_t)4096*256*2;
  float* hfinal  = (float*)(ws + o); o += (size_t)32*256*4;
  float* hdec    = (float*)(ws + o); o += (size_t)4096*256*4;
  unsigned short* attn_o  = (unsigned short*)(ws + o); o += (size_t)4096*256*2;
  unsigned short* Wout_bf = (unsigned short*)(ws + o); o += (size_t)V_*256*2;
  unsigned short* Wattn_bf= (unsigned short*)(ws + o); o += (size_t)256*512*2;

  k_cvt<<<8000, 256, 0, stream>>>(W_out, Wout_bf, 2048000);
  k_cvt<<<128, 256, 0, stream>>>(W_attn, Wattn_bf, 32768);
  k_xih<<<256, 256, 0, stream>>>(indices_de, emb_enc, W_ih_enc, b_ih_enc, b_hh_enc, Xih_enc);
  k_xih<<<256, 256, 0, stream>>>(indices_en, emb_dec, W_ih_dec, b_ih_dec, b_hh_dec, Xih_dec);
  k_rnn<1><<<32, 512, 0, stream>>>(W_hh_enc, Xih_enc, nullptr, lengths_de, enc_bf, nullptr, hfinal);
  k_rnn<0><<<32, 512, 0, stream>>>(W_hh_dec, Xih_dec, hfinal, nullptr, nullptr, hdec, nullptr);
  k_attn<<<256, 256, 0, stream>>>(enc_bf, hdec, lengths_de, Wattn_bf, b_attn, attn_o);
  dim3 gD(250, 32);
  k_vocab<<<gD, 256, 0, stream>>>(attn_o, Wout_bf, b_out, (float*)d_out);
}